// Round 6
// baseline (418.551 us; speedup 1.0000x reference)
//
#include <hip/hip_runtime.h>
#include <cstdint>

// MXFP4 fake-quant linear: out = qdq(A) @ qdq(W)^T + bias
// Stage 1: quantize fp32 -> packed e2m1 + e8m0 scales (TRANSPOSED scale
//          layout AscT[kblk][m], WscT[kblk][n]; verified rounds 3-5).
// Stage 2: fp4 GEMM, 128x128 tile, 4 waves 2x2, 32x32x64 scaled MFMA,
//          SINGLE barrier per K-tile: A = 3-deep LDS ring (staged t+2),
//          B = 2-deep ring (staged t+1), scales prefetched 1 tile ahead
//          into rotating register banks, one counted vmcnt(2)/tile,
//          XCD-aware remap, 4 WGs/CU (40 KB LDS).

#define BM 128
#define BN 128
#define BK 128      // K elements per tile = 2 k-steps of the 32x32x64 MFMA

typedef float floatx16 __attribute__((ext_vector_type(16)));
typedef int intx8 __attribute__((ext_vector_type(8)));

#define GLOBAL_AS __attribute__((address_space(1)))
#define LDS_AS __attribute__((address_space(3)))

// ---------------- quantize fp32 -> packed fp4 + e8m0 scales ----------------

__device__ __forceinline__ int enc1(float x, float inv) {
    float q = x * inv;                         // inv = 2^-(e-2), exact
    q = fminf(fmaxf(q, -6.0f), 6.0f);
    int s = (int)(__float_as_uint(q) >> 31) << 3;
    float aq = fabsf(q);
    float ilsb = aq < 2.0f ? 2.0f : (aq < 4.0f ? 1.0f : 0.5f);
    float lsb  = aq < 2.0f ? 0.5f : (aq < 4.0f ? 1.0f : 2.0f);
    float ar = rintf(aq * ilsb) * lsb;         // RNE onto e2m1 grid
    int c;
    if (ar < 2.0f)      c = (int)(ar * 2.0f);  // 0,.5,1,1.5 -> 0..3
    else if (ar < 4.0f) c = 2 + (int)ar;       // 2,3 -> 4,5
    else                c = 4 + (int)(ar * 0.5f); // 4,6 -> 6,7
    return c | s;
}

__global__ void quant_mxfp4_v4(const float* __restrict__ A, uint8_t* __restrict__ Aq,
                               uint8_t* __restrict__ AscT,
                               const float* __restrict__ W, uint8_t* __restrict__ Wq,
                               uint8_t* __restrict__ WscT,
                               long na4, long ntot4, int s4, long Mr, long Nr) {
    long t = (long)blockIdx.x * 256 + threadIdx.x;
    if (t >= ntot4) return;
    const float* src; uint8_t* dq; uint8_t* ds; long idx; long rows;
    if (t < na4) { src = A; dq = Aq; ds = AscT; idx = t; rows = Mr; }
    else         { src = W; dq = Wq; ds = WscT; idx = t - na4; rows = Nr; }

    float4 f = ((const float4*)src)[idx];
    float amax = fmaxf(fmaxf(fabsf(f.x), fabsf(f.y)),
                       fmaxf(fabsf(f.z), fabsf(f.w)));
    amax = fmaxf(amax, __shfl_xor(amax, 1));
    amax = fmaxf(amax, __shfl_xor(amax, 2));
    amax = fmaxf(amax, __shfl_xor(amax, 4));

    int ebits = (int)((__float_as_uint(amax) >> 23) & 0xff);
    int sb;
    float inv;
    if (amax > 0.0f) {
        sb = ebits - 2; if (sb < 0) sb = 0;
        inv = __uint_as_float((unsigned)((256 - ebits) & 255) << 23);
    } else {
        sb = 127;              // scale 1.0, all-zero block
        inv = 0.0f;
    }

    int c0 = enc1(f.x, inv), c1 = enc1(f.y, inv);
    int c2 = enc1(f.z, inv), c3 = enc1(f.w, inv);
    ((unsigned short*)dq)[idx] =
        (unsigned short)(c0 | (c1 << 4) | (c2 << 8) | (c3 << 12));
    if ((idx & 7) == 0) {
        long m  = idx >> s4;                       // row
        int  kb = (int)((idx & ((1L << s4) - 1)) >> 3);  // k-block
        ds[(size_t)kb * rows + m] = (uint8_t)sb;   // transposed: [kb][row]
    }
}

// ---------- fp4 GEMM: C[M,N] = (Aq,AscT) x (Wq,WscT)^T + bias ----------
// 256 threads = 4 waves 2(M) x 2(N); per-wave output 64x64 = acc[2][2] of
// 32x32 blocks (16 f32 each).
// 32x32x64 frag: A row = lane&31, k-block (32 elems, 16B) = lane>>5;
//                B col = lane&31 (= W row), same k-split.
// C/D: col = lane&31 (n), row = (reg&3) + 8*(reg>>2) + 4*(lane>>5) (m).
// LDS rows 64B = 4 x 16B chunks; slot c holds global chunk c^((row>>1)&3)
// (applied on DMA source AND on read). All verified in round 5.
//
// Sync design (1 barrier/tile): each wave's ds_reads of tile t are fully
// drained (lgkmcnt(0)) before it reaches barrier(t). So after barrier(t),
// bufA t%3 and bufB t&1 are free. At tile t we stage A(t+2) -> bufA
// (t+2)%3 (freed at barrier(t-1)) and B(t+1) -> bufB (t+1)&1 (freed at
// barrier(t-1)). End-of-tile: issue order [scales(t+1)x8, B(t+1)x2,
// A(t+2)x2] pinned by sched_barrier => vmcnt(2) waits everything except
// A(t+2); barrier then makes all waves' DMA(t+1)+scales(t+1) visible.

__global__ __launch_bounds__(256, 4) void gemm_fp4_v7(
        const uint8_t* __restrict__ Aq, const uint8_t* __restrict__ AscT,
        const uint8_t* __restrict__ Wq, const uint8_t* __restrict__ WscT,
        const float* __restrict__ bias, float* __restrict__ C,
        int M, int N, int K) {
    __shared__ __align__(16) uint8_t sAb[3][BM * 64];  // 24 KB, ring of 3
    __shared__ __align__(16) uint8_t sBb[2][BN * 64];  // 16 KB, ring of 2

    const int tid = threadIdx.x;
    const int lane = tid & 63;
    const int w = tid >> 6;
    const int wr = w >> 1;           // 0..1 (M)
    const int wc = w & 1;            // 0..1 (N)
    const int row32 = lane & 31;
    const int q2 = lane >> 5;        // k-block half within a 64-K step

    // XCD-aware bijective remap (grid 1024, id%8 = XCD)
    const int id = blockIdx.x;
    const int g = id & 7, h = id >> 3;
    const int by = g + 8 * (h & 7);  // 0..63
    const int bx = h >> 3;           // 0..15
    const int m0 = by * BM;
    const int n0 = bx * BN;
    const int KB2 = K >> 1;
    const int NT = K / BK;           // 16 (even)

    const int rA = wr * 64 + row32;  // A row within tile
    const int rB = wc * 64 + row32;  // B row within tile
    const int swz = (row32 >> 1) & 3;
    const int off0 = ((0 + q2) ^ swz) * 16;   // ks=0 chunk
    const int off1 = ((2 + q2) ^ swz) * 16;   // ks=1 chunk

    floatx16 acc[2][2];
#pragma unroll
    for (int i = 0; i < 2; i++)
#pragma unroll
        for (int j = 0; j < 2; j++)
#pragma unroll
            for (int r = 0; r < 16; r++) acc[i][j][r] = 0.f;

    auto stageA = [&](int tt) {      // 2 x 16B DMA insts
        const int bb = tt % 3;
        const int kb = tt * 64;
#pragma unroll
        for (int it = 0; it < 2; ++it) {
            int idx = it * 256 + tid;           // 0..511 16B chunks
            int row = idx >> 2, c = idx & 3;
            int gc = c ^ ((row >> 1) & 3);
            const uint8_t* src = Aq + (size_t)(m0 + row) * KB2 + kb + gc * 16;
            __builtin_amdgcn_global_load_lds((GLOBAL_AS void*)src,
                (LDS_AS void*)(&sAb[bb][idx * 16]), 16, 0, 0);
        }
    };
    auto stageB = [&](int tt) {      // 2 x 16B DMA insts
        const int bb = tt & 1;
        const int kb = tt * 64;
#pragma unroll
        for (int it = 0; it < 2; ++it) {
            int idx = it * 256 + tid;
            int row = idx >> 2, c = idx & 3;
            int gc = c ^ ((row >> 1) & 3);
            const uint8_t* src = Wq + (size_t)(n0 + row) * KB2 + kb + gc * 16;
            __builtin_amdgcn_global_load_lds((GLOBAL_AS void*)src,
                (LDS_AS void*)(&sBb[bb][idx * 16]), 16, 0, 0);
        }
    };
    auto loadScales = [&](int tt, int (&sa)[2][2], int (&sb)[2][2]) {
        // e8m0 byte of k-block (4*tt + 2*ks + q2), row (m0|n0 + sub)
#pragma unroll
        for (int ks = 0; ks < 2; ++ks)
#pragma unroll
            for (int i = 0; i < 2; ++i) {
                sa[ks][i] = (int)AscT[(size_t)(4 * tt + 2 * ks + q2) * M +
                                      m0 + wr * 64 + i * 32 + row32];
                sb[ks][i] = (int)WscT[(size_t)(4 * tt + 2 * ks + q2) * N +
                                      n0 + wc * 64 + i * 32 + row32];
            }
    };

    // persistent zero-padded operand tuples (upper 4 regs stay 0)
    intx8 a0 = {0,0,0,0,0,0,0,0}, a1 = a0, b0 = a0, b1 = a0;

    // one tile: reads+MFMA on (saU,sbU); prefetch scales(t+1) into (saL,sbL)
    auto tile = [&](int t, int (&saU)[2][2], int (&sbU)[2][2],
                    int (&saL)[2][2], int (&sbL)[2][2]) {
        const uint8_t* pa = sAb[t % 3];
        const uint8_t* pb = sBb[t & 1];

        // 8 x ds_read_b128 fragment reads (lgkm)
        int4 fa[2][2], fb[2][2];
#pragma unroll
        for (int i = 0; i < 2; ++i) {
            fa[0][i] = *(const int4*)(pa + (rA + i * 32) * 64 + off0);
            fa[1][i] = *(const int4*)(pa + (rA + i * 32) * 64 + off1);
            fb[0][i] = *(const int4*)(pb + (rB + i * 32) * 64 + off0);
            fb[1][i] = *(const int4*)(pb + (rB + i * 32) * 64 + off1);
        }

        // VMEM issue order pinned: scales(t+1), B(t+1), A(t+2)
        if (t + 1 < NT) loadScales(t + 1, saL, sbL);
        __builtin_amdgcn_sched_barrier(0);
        if (t + 1 < NT) stageB(t + 1);
        __builtin_amdgcn_sched_barrier(0);
        if (t + 2 < NT) stageA(t + 2);
        __builtin_amdgcn_sched_barrier(0);

        asm volatile("s_waitcnt lgkmcnt(0)" ::: "memory");
        __builtin_amdgcn_sched_barrier(0);

        __builtin_amdgcn_s_setprio(1);
#pragma unroll
        for (int ks = 0; ks < 2; ++ks) {
            const int4 fA0 = fa[ks][0], fA1 = fa[ks][1];
            const int4 fB0 = fb[ks][0], fB1 = fb[ks][1];
            a0[0] = fA0.x; a0[1] = fA0.y; a0[2] = fA0.z; a0[3] = fA0.w;
            a1[0] = fA1.x; a1[1] = fA1.y; a1[2] = fA1.z; a1[3] = fA1.w;
            b0[0] = fB0.x; b0[1] = fB0.y; b0[2] = fB0.z; b0[3] = fB0.w;
            b1[0] = fB1.x; b1[1] = fB1.y; b1[2] = fB1.z; b1[3] = fB1.w;
            acc[0][0] = __builtin_amdgcn_mfma_scale_f32_32x32x64_f8f6f4(
                a0, b0, acc[0][0], 4, 4, 0, saU[ks][0], 0, sbU[ks][0]);
            acc[0][1] = __builtin_amdgcn_mfma_scale_f32_32x32x64_f8f6f4(
                a0, b1, acc[0][1], 4, 4, 0, saU[ks][0], 0, sbU[ks][1]);
            acc[1][0] = __builtin_amdgcn_mfma_scale_f32_32x32x64_f8f6f4(
                a1, b0, acc[1][0], 4, 4, 0, saU[ks][1], 0, sbU[ks][0]);
            acc[1][1] = __builtin_amdgcn_mfma_scale_f32_32x32x64_f8f6f4(
                a1, b1, acc[1][1], 4, 4, 0, saU[ks][1], 0, sbU[ks][1]);
        }
        __builtin_amdgcn_s_setprio(0);

        // one counted wait + one barrier per tile
        if (t + 2 < NT)      asm volatile("s_waitcnt vmcnt(2)" ::: "memory");
        else if (t + 1 < NT) asm volatile("s_waitcnt vmcnt(0)" ::: "memory");
        __builtin_amdgcn_sched_barrier(0);
        if (t + 1 < NT) __builtin_amdgcn_s_barrier();
    };

    int sa0[2][2], sb0[2][2], sa1[2][2], sb1[2][2];

    // ---- prologue: A(0), B(0), scales(0), A(1); wait all but A(1) ----
    stageA(0);
    __builtin_amdgcn_sched_barrier(0);
    stageB(0);
    __builtin_amdgcn_sched_barrier(0);
    loadScales(0, sa0, sb0);
    __builtin_amdgcn_sched_barrier(0);
    stageA(1);
    __builtin_amdgcn_sched_barrier(0);
    asm volatile("s_waitcnt vmcnt(2)" ::: "memory");
    __builtin_amdgcn_sched_barrier(0);
    __builtin_amdgcn_s_barrier();

    for (int t = 0; t < NT; t += 2) {
        tile(t,     sa0, sb0, sa1, sb1);
        tile(t + 1, sa1, sb1, sa0, sb0);
    }

    // ---- epilogue: col = lane&31 (n), row = (r&3)+8*(r>>2)+4*q2 (m) ----
#pragma unroll
    for (int j = 0; j < 2; ++j) {
        int n = n0 + wc * 64 + j * 32 + row32;
        float bv = bias[n];
#pragma unroll
        for (int i = 0; i < 2; ++i) {
            int mb = m0 + wr * 64 + i * 32 + 4 * q2;
#pragma unroll
            for (int r = 0; r < 16; ++r) {
                int m = mb + (r & 3) + 8 * (r >> 2);
                C[(size_t)m * N + n] = acc[i][j][r] + bv;
            }
        }
    }
}

// ---------------- launch ----------------

extern "C" void kernel_launch(void* const* d_in, const int* in_sizes, int n_in,
                              void* d_out, int out_size, void* d_ws, size_t ws_size,
                              hipStream_t stream) {
    const float* inp  = (const float*)d_in[0];
    const float* wgt  = (const float*)d_in[1];
    const float* bias = (const float*)d_in[2];
    float* out = (float*)d_out;

    const int N = in_sizes[2];                 // 2048
    const int K = in_sizes[1] / N;             // 2048
    const long M = (long)in_sizes[0] / K;      // 8192

    uint8_t* Aq4  = (uint8_t*)d_ws;            // M*K/2
    uint8_t* Wq4  = Aq4 + (size_t)M * K / 2;   // N*K/2
    uint8_t* AscT = Wq4 + (size_t)N * K / 2;   // M*K/32 (layout [K/32][M])
    uint8_t* WscT = AscT + (size_t)M * K / 32; // N*K/32 (layout [K/32][N])

    int s4 = 0;
    while ((1 << s4) < (K >> 2)) ++s4;         // log2(K/4) = 9

    long na4   = (long)M * K / 4;
    long ntot4 = na4 + (long)N * K / 4;
    quant_mxfp4_v4<<<dim3((ntot4 + 255) / 256), dim3(256), 0, stream>>>(
        inp, Aq4, AscT, wgt, Wq4, WscT, na4, ntot4, s4, M, (long)N);

    dim3 grid((N / BN) * (int)(M / BM));       // 16*64 = 1024 = 4/CU
    gemm_fp4_v7<<<grid, dim3(256), 0, stream>>>(
        Aq4, AscT, Wq4, WscT, bias, out, (int)M, N, K);
}

// Round 10
// 152.645 us; speedup vs baseline: 2.7420x; 2.7420x over previous
//
#include <hip/hip_runtime.h>
#include <cstdint>

// MXFP4 fake-quant linear: out = qdq(A) @ qdq(W)^T + bias
// Stage 1: quantize fp32 -> packed e2m1 + e8m0 scales (TRANSPOSED scale
//          layout AscT[kblk][m], WscT[kblk][n]; verified rounds 3-5).
// Stage 2: fp4 GEMM, 128x128 tile, BK=256 per sync iteration (4 k-steps of
//          the 32x32x64 scaled MFMA, 16 MFMA/wave/iter, NT=8), double-
//          buffered 64 KB LDS, 2 WGs/CU, reg-scales, XOR swizzle
//          c^(row&7), XCD remap, counted vmcnt skeleton from r5.
// (3rd resubmission: rounds 7-9 all failed on infra -- container crash,
//  then two GPU acquisition timeouts. Kernel unchanged, audited in r7.)

#define BM 128
#define BN 128
#define BK 256      // K elements per sync iteration = 4 k-steps

typedef float floatx16 __attribute__((ext_vector_type(16)));
typedef int intx8 __attribute__((ext_vector_type(8)));

#define GLOBAL_AS __attribute__((address_space(1)))
#define LDS_AS __attribute__((address_space(3)))

// ---------------- quantize fp32 -> packed fp4 + e8m0 scales ----------------

__device__ __forceinline__ int enc1(float x, float inv) {
    float q = x * inv;                         // inv = 2^-(e-2), exact
    q = fminf(fmaxf(q, -6.0f), 6.0f);
    int s = (int)(__float_as_uint(q) >> 31) << 3;
    float aq = fabsf(q);
    float ilsb = aq < 2.0f ? 2.0f : (aq < 4.0f ? 1.0f : 0.5f);
    float lsb  = aq < 2.0f ? 0.5f : (aq < 4.0f ? 1.0f : 2.0f);
    float ar = rintf(aq * ilsb) * lsb;         // RNE onto e2m1 grid
    int c;
    if (ar < 2.0f)      c = (int)(ar * 2.0f);  // 0,.5,1,1.5 -> 0..3
    else if (ar < 4.0f) c = 2 + (int)ar;       // 2,3 -> 4,5
    else                c = 4 + (int)(ar * 0.5f); // 4,6 -> 6,7
    return c | s;
}

__global__ void quant_mxfp4_v4(const float* __restrict__ A, uint8_t* __restrict__ Aq,
                               uint8_t* __restrict__ AscT,
                               const float* __restrict__ W, uint8_t* __restrict__ Wq,
                               uint8_t* __restrict__ WscT,
                               long na4, long ntot4, int s4, long Mr, long Nr) {
    long t = (long)blockIdx.x * 256 + threadIdx.x;
    if (t >= ntot4) return;
    const float* src; uint8_t* dq; uint8_t* ds; long idx; long rows;
    if (t < na4) { src = A; dq = Aq; ds = AscT; idx = t; rows = Mr; }
    else         { src = W; dq = Wq; ds = WscT; idx = t - na4; rows = Nr; }

    float4 f = ((const float4*)src)[idx];
    float amax = fmaxf(fmaxf(fabsf(f.x), fabsf(f.y)),
                       fmaxf(fabsf(f.z), fabsf(f.w)));
    amax = fmaxf(amax, __shfl_xor(amax, 1));
    amax = fmaxf(amax, __shfl_xor(amax, 2));
    amax = fmaxf(amax, __shfl_xor(amax, 4));

    int ebits = (int)((__float_as_uint(amax) >> 23) & 0xff);
    int sb;
    float inv;
    if (amax > 0.0f) {
        sb = ebits - 2; if (sb < 0) sb = 0;
        inv = __uint_as_float((unsigned)((256 - ebits) & 255) << 23);
    } else {
        sb = 127;              // scale 1.0, all-zero block
        inv = 0.0f;
    }

    int c0 = enc1(f.x, inv), c1 = enc1(f.y, inv);
    int c2 = enc1(f.z, inv), c3 = enc1(f.w, inv);
    ((unsigned short*)dq)[idx] =
        (unsigned short)(c0 | (c1 << 4) | (c2 << 8) | (c3 << 12));
    if ((idx & 7) == 0) {
        long m  = idx >> s4;                       // row
        int  kb = (int)((idx & ((1L << s4) - 1)) >> 3);  // k-block
        ds[(size_t)kb * rows + m] = (uint8_t)sb;   // transposed: [kb][row]
    }
}

// ---------- fp4 GEMM: C[M,N] = (Aq,AscT) x (Wq,WscT)^T + bias ----------
// 256 threads = 4 waves 2(M) x 2(N); per-wave output 64x64 = acc[2][2] of
// 32x32 blocks (16 f32 each).
// 32x32x64 frag: A row = lane&31, k-block (32 elems, 16B) = lane>>5;
//                B col = lane&31 (= W row), same k-split.
// C/D: col = lane&31 (n), row = (reg&3) + 8*(reg>>2) + 4*(lane>>5) (m).
// LDS rows are 128B = 8 x 16B chunks; slot c holds global chunk c^(row&7)
// (applied on DMA source AND on read): a frag read's 64 lanes spread
// 8 lanes x 16B per 4-bank group (balanced, minimum service time).
//
// Sync per iteration (BK=256, buf p = t&1):
//   scales(t) 16 ubyte loads -> ds_reads(t) 16 x b128 -> lgkmcnt(0)
//   -> barrier1 (buf p readers done) -> stage(t+2) into p (8 DMA)
//   -> vmcnt(8): scales(t)+stage(t+1) landed, stage(t+2) in flight
//   -> 16 MFMA -> vmcnt(8) -> barrier2.
// No full drain in the main loop.

__global__ __launch_bounds__(256, 2) void gemm_fp4_v8(
        const uint8_t* __restrict__ Aq, const uint8_t* __restrict__ AscT,
        const uint8_t* __restrict__ Wq, const uint8_t* __restrict__ WscT,
        const float* __restrict__ bias, float* __restrict__ C,
        int M, int N, int K) {
    __shared__ __align__(16) uint8_t sA[2][BM * 128];  // 2 x 16 KB
    __shared__ __align__(16) uint8_t sB[2][BN * 128];  // 2 x 16 KB

    const int tid = threadIdx.x;
    const int lane = tid & 63;
    const int w = tid >> 6;
    const int wr = w >> 1;           // 0..1 (M)
    const int wc = w & 1;            // 0..1 (N)
    const int row32 = lane & 31;
    const int q2 = lane >> 5;        // k-block half within a 64-K step

    // XCD-aware bijective remap (grid 1024, id%8 = XCD)
    const int id = blockIdx.x;
    const int g = id & 7, h = id >> 3;
    const int by = g + 8 * (h & 7);  // 0..63
    const int bx = h >> 3;           // 0..15
    const int m0 = by * BM;
    const int n0 = bx * BN;
    const int KB2 = K >> 1;
    const int NT = K / BK;           // 8

    const int rA = wr * 64 + row32;  // A row within tile
    const int rB = wc * 64 + row32;  // B row within tile
    const int swz = row32 & 7;       // read-side swizzle (row-dependent)

    floatx16 acc[2][2];
#pragma unroll
    for (int i = 0; i < 2; i++)
#pragma unroll
        for (int j = 0; j < 2; j++)
#pragma unroll
            for (int r = 0; r < 16; r++) acc[i][j][r] = 0.f;

    // 8 uniform DMA insts per thread per iteration: 4 A + 4 B (16B each)
    auto stage = [&](int tt) {
        const int bb = tt & 1;
        const int kb = tt * 128;                // byte offset along packed K
#pragma unroll
        for (int it = 0; it < 4; ++it) {
            int idx = it * 256 + tid;           // 0..1023 16B chunks
            int row = idx >> 3, c = idx & 7;
            int gc = c ^ (row & 7);             // pre-swizzled source chunk
            const uint8_t* src = Aq + (size_t)(m0 + row) * KB2 + kb + gc * 16;
            __builtin_amdgcn_global_load_lds((GLOBAL_AS void*)src,
                (LDS_AS void*)(&sA[bb][idx * 16]), 16, 0, 0);
        }
#pragma unroll
        for (int it = 0; it < 4; ++it) {
            int idx = it * 256 + tid;
            int row = idx >> 3, c = idx & 7;
            int gc = c ^ (row & 7);
            const uint8_t* src = Wq + (size_t)(n0 + row) * KB2 + kb + gc * 16;
            __builtin_amdgcn_global_load_lds((GLOBAL_AS void*)src,
                (LDS_AS void*)(&sB[bb][idx * 16]), 16, 0, 0);
        }
    };

    // ---- prologue: stage tiles 0,1; tile 0 landed, tile 1 in flight ----
    stage(0);
    stage(1);
    asm volatile("s_waitcnt vmcnt(8)" ::: "memory");
    __builtin_amdgcn_sched_barrier(0);
    __builtin_amdgcn_s_barrier();

    for (int t = 0; t < NT; ++t) {
        const int p = t & 1;
        const uint8_t* pa = sA[p];
        const uint8_t* pb = sB[p];

        // scales for iteration t: 16 coalesced ubyte loads (vm counter)
        int sa[4][2], sb[4][2];
#pragma unroll
        for (int ks = 0; ks < 4; ++ks)
#pragma unroll
            for (int i = 0; i < 2; ++i) {
                sa[ks][i] = (int)AscT[(size_t)(8 * t + 2 * ks + q2) * M +
                                      m0 + wr * 64 + i * 32 + row32];
                sb[ks][i] = (int)WscT[(size_t)(8 * t + 2 * ks + q2) * N +
                                      n0 + wc * 64 + i * 32 + row32];
            }

        // fragment reads: 16 x ds_read_b128 (lgkm counter)
        int4 fa[4][2], fb[4][2];
#pragma unroll
        for (int ks = 0; ks < 4; ++ks) {
            int off = ((ks * 2 + q2) ^ swz) * 16;
#pragma unroll
            for (int i = 0; i < 2; ++i) {
                fa[ks][i] = *(const int4*)(pa + (rA + i * 32) * 128 + off);
                fb[ks][i] = *(const int4*)(pb + (rB + i * 32) * 128 + off);
            }
        }

        asm volatile("s_waitcnt lgkmcnt(0)" ::: "memory");
        __builtin_amdgcn_sched_barrier(0);
        __builtin_amdgcn_s_barrier();       // all waves done reading buf p

        if (t + 2 < NT) stage(t + 2);       // overwrite buf p (just freed)

        // scales(t) + stage(t+1) landed; stage(t+2) stays in flight
        if (t + 2 < NT) asm volatile("s_waitcnt vmcnt(8)" ::: "memory");
        else            asm volatile("s_waitcnt vmcnt(0)" ::: "memory");
        __builtin_amdgcn_sched_barrier(0);

        __builtin_amdgcn_s_setprio(1);
#pragma unroll
        for (int ks = 0; ks < 4; ++ks) {
            intx8 a0, a1, b0, b1;
            a0[0] = fa[ks][0].x; a0[1] = fa[ks][0].y; a0[2] = fa[ks][0].z; a0[3] = fa[ks][0].w;
            a1[0] = fa[ks][1].x; a1[1] = fa[ks][1].y; a1[2] = fa[ks][1].z; a1[3] = fa[ks][1].w;
            b0[0] = fb[ks][0].x; b0[1] = fb[ks][0].y; b0[2] = fb[ks][0].z; b0[3] = fb[ks][0].w;
            b1[0] = fb[ks][1].x; b1[1] = fb[ks][1].y; b1[2] = fb[ks][1].z; b1[3] = fb[ks][1].w;
#pragma unroll
            for (int z = 4; z < 8; ++z) { a0[z] = 0; a1[z] = 0; b0[z] = 0; b1[z] = 0; }
            acc[0][0] = __builtin_amdgcn_mfma_scale_f32_32x32x64_f8f6f4(
                a0, b0, acc[0][0], 4, 4, 0, sa[ks][0], 0, sb[ks][0]);
            acc[0][1] = __builtin_amdgcn_mfma_scale_f32_32x32x64_f8f6f4(
                a0, b1, acc[0][1], 4, 4, 0, sa[ks][0], 0, sb[ks][1]);
            acc[1][0] = __builtin_amdgcn_mfma_scale_f32_32x32x64_f8f6f4(
                a1, b0, acc[1][0], 4, 4, 0, sa[ks][1], 0, sb[ks][0]);
            acc[1][1] = __builtin_amdgcn_mfma_scale_f32_32x32x64_f8f6f4(
                a1, b1, acc[1][1], 4, 4, 0, sa[ks][1], 0, sb[ks][1]);
        }
        __builtin_amdgcn_s_setprio(0);

        // stage(t+1) fully landed before anyone reads buf p^1 next iter
        if (t < NT - 1) {
            if (t + 2 < NT) asm volatile("s_waitcnt vmcnt(8)" ::: "memory");
            else            asm volatile("s_waitcnt vmcnt(0)" ::: "memory");
            __builtin_amdgcn_sched_barrier(0);
            __builtin_amdgcn_s_barrier();
        }
    }

    // ---- epilogue: col = lane&31 (n), row = (r&3)+8*(r>>2)+4*q2 (m) ----
#pragma unroll
    for (int j = 0; j < 2; ++j) {
        int n = n0 + wc * 64 + j * 32 + row32;
        float bv = bias[n];
#pragma unroll
        for (int i = 0; i < 2; ++i) {
            int mb = m0 + wr * 64 + i * 32 + 4 * q2;
#pragma unroll
            for (int r = 0; r < 16; ++r) {
                int m = mb + (r & 3) + 8 * (r >> 2);
                C[(size_t)m * N + n] = acc[i][j][r] + bv;
            }
        }
    }
}

// ---------------- launch ----------------

extern "C" void kernel_launch(void* const* d_in, const int* in_sizes, int n_in,
                              void* d_out, int out_size, void* d_ws, size_t ws_size,
                              hipStream_t stream) {
    const float* inp  = (const float*)d_in[0];
    const float* wgt  = (const float*)d_in[1];
    const float* bias = (const float*)d_in[2];
    float* out = (float*)d_out;

    const int N = in_sizes[2];                 // 2048
    const int K = in_sizes[1] / N;             // 2048
    const long M = (long)in_sizes[0] / K;      // 8192

    uint8_t* Aq4  = (uint8_t*)d_ws;            // M*K/2
    uint8_t* Wq4  = Aq4 + (size_t)M * K / 2;   // N*K/2
    uint8_t* AscT = Wq4 + (size_t)N * K / 2;   // M*K/32 (layout [K/32][M])
    uint8_t* WscT = AscT + (size_t)M * K / 32; // N*K/32 (layout [K/32][N])

    int s4 = 0;
    while ((1 << s4) < (K >> 2)) ++s4;         // log2(K/4) = 9

    long na4   = (long)M * K / 4;
    long ntot4 = na4 + (long)N * K / 4;
    quant_mxfp4_v4<<<dim3((ntot4 + 255) / 256), dim3(256), 0, stream>>>(
        inp, Aq4, AscT, wgt, Wq4, WscT, na4, ntot4, s4, M, (long)N);

    dim3 grid((N / BN) * (int)(M / BM));       // 16*64 = 1024 = 2/CU tail-free
    gemm_fp4_v8<<<grid, dim3(256), 0, stream>>>(
        Aq4, AscT, Wq4, WscT, bias, out, (int)M, N, K);
}